// Round 4
// baseline (221.759 us; speedup 1.0000x reference)
//
#include <hip/hip_runtime.h>
#include <cstdint>
#include <cstddef>

#define BATCH   4
#define SEQ     4096
#define HIDDEN  4096
#define RANK    512
#define OUTF    4096
#define SROWS   4097              // seq+1
#define MROWS   (BATCH * SROWS)   // 16388

typedef int v4i __attribute__((ext_vector_type(4)));

#define AS1 __attribute__((address_space(1)))
#define AS3 __attribute__((address_space(3)))

// ---------------------------------------------------------------------------
// Kernel 1: new_latent[b][r] = dot(new_x[b,0,:], B_weight[r,:])
// ---------------------------------------------------------------------------
__global__ void k_new_latent(const float* __restrict__ newx,
                             const float* __restrict__ Bw,
                             float* __restrict__ out_latent) {
    int wave = threadIdx.x >> 6;
    int lane = threadIdx.x & 63;
    int pair = blockIdx.x * 4 + wave;   // 0..2047
    int b = pair >> 9;
    int r = pair & 511;
    const float4* x4 = (const float4*)(newx + (size_t)b * HIDDEN);
    const float4* w4 = (const float4*)(Bw + (size_t)r * HIDDEN);
    float sum = 0.f;
#pragma unroll
    for (int j = 0; j < 16; ++j) {
        float4 xv = x4[lane + 64 * j];
        float4 wv = w4[lane + 64 * j];
        sum += xv.x * wv.x + xv.y * wv.y + xv.z * wv.z + xv.w * wv.w;
    }
#pragma unroll
    for (int off = 32; off >= 1; off >>= 1)
        sum += __shfl_xor(sum, off, 64);
    if (lane == 0) {
        out_latent[(size_t)(b * SROWS + SEQ) * RANK + r] = sum;
    }
}

// ---------------------------------------------------------------------------
// Kernel 2: per-row int8 quant (rank=512) + copy cached rows to output.
// ---------------------------------------------------------------------------
__global__ void k_quant(const float* __restrict__ cached,
                        float* __restrict__ out_latent,
                        int8_t* __restrict__ Qq,
                        float* __restrict__ scales) {
    int m = blockIdx.x * 4 + (threadIdx.x >> 6);   // 0..16387
    int lane = threadIdx.x & 63;
    int b = m / SROWS;
    int s = m - b * SROWS;
    const float* src = (s < SEQ) ? (cached + ((size_t)b * SEQ + s) * RANK)
                                 : (out_latent + (size_t)m * RANK);
    float4 v0 = ((const float4*)src)[lane];
    float4 v1 = ((const float4*)src)[64 + lane];
    float am = fmaxf(fmaxf(fmaxf(fabsf(v0.x), fabsf(v0.y)),
                           fmaxf(fabsf(v0.z), fabsf(v0.w))),
                     fmaxf(fmaxf(fabsf(v1.x), fabsf(v1.y)),
                           fmaxf(fabsf(v1.z), fabsf(v1.w))));
#pragma unroll
    for (int off = 32; off >= 1; off >>= 1)
        am = fmaxf(am, __shfl_xor(am, off, 64));
    am = fmaxf(am, 1e-8f);
    float scale = am / 127.0f;

    auto qp = [&](float x) -> uint32_t {
        float r = rintf(x / scale);          // round-half-even, matches jnp.round
        r = fminf(fmaxf(r, -128.0f), 127.0f);
        return (uint32_t)(uint8_t)(int8_t)(int)r;
    };
    uint32_t p0 = qp(v0.x) | (qp(v0.y) << 8) | (qp(v0.z) << 16) | (qp(v0.w) << 24);
    uint32_t p1 = qp(v1.x) | (qp(v1.y) << 8) | (qp(v1.z) << 16) | (qp(v1.w) << 24);
    uint32_t* qrow = (uint32_t*)(Qq + (size_t)m * RANK);
    qrow[lane] = p0;
    qrow[64 + lane] = p1;
    if (s < SEQ) {
        float4* dst = (float4*)(out_latent + (size_t)m * RANK);
        dst[lane] = v0;
        dst[64 + lane] = v1;
    }
    if (lane == 0) scales[m] = scale;
}

// ---------------------------------------------------------------------------
// Kernel 3: pack A_int8 (int32 storage, 4096x512) -> int8 bytes.
// ---------------------------------------------------------------------------
__global__ void k_packA(const int* __restrict__ Ai, uint8_t* __restrict__ Ap) {
    int idx = blockIdx.x * blockDim.x + threadIdx.x;
    int4 v = ((const int4*)Ai)[idx];
    uint32_t p = (uint32_t)(v.x & 0xff) | ((uint32_t)(v.y & 0xff) << 8) |
                 ((uint32_t)(v.z & 0xff) << 16) | ((uint32_t)(v.w & 0xff) << 24);
    ((uint32_t*)Ap)[idx] = p;
}

// ---------------------------------------------------------------------------
// Kernel 4: int8 GEMM + dequant. Full-K-in-LDS, single barrier.
//   128x128 output tile, full K=512 of Q-tile and A-tile staged in LDS
//   (64 KiB + 64 KiB). XOR chunk swizzle: LDS[row][s] holds global chunk
//   s ^ (row & 31), making ds_read_b128 fragment reads 2-way (free).
//   4 waves, each a 64x64 sub-tile = 4x4 frags of mfma_i32_16x16x64_i8,
//   8 unrolled K-steps, no inner barriers.
// ---------------------------------------------------------------------------
#define BM 128
#define BN 128
#define NT_N (OUTF / BN)   // 32

__launch_bounds__(256, 1)
__global__ void k_gemm(const int8_t* __restrict__ Qq,
                       const int8_t* __restrict__ Ap,
                       const float* __restrict__ scales,
                       const float* __restrict__ Ascale,
                       float* __restrict__ out,
                       int M) {
    __shared__ __align__(16) int8_t Qs[BM * RANK];   // 64 KiB
    __shared__ __align__(16) int8_t As[BN * RANK];   // 64 KiB

    // XCD-bijective blockIdx swizzle (gridDim.x = 4128, % 8 == 0): each XCD
    // gets a contiguous swz stripe -> concurrent blocks share one Q-tile in L2.
    int per = gridDim.x >> 3;
    int bid = blockIdx.x;
    int swz = (bid & 7) * per + (bid >> 3);
    int tn = swz & (NT_N - 1);
    int tm = swz / NT_N;

    int tid = threadIdx.x;
    int lane = tid & 63;
    int wave = tid >> 6;
    int wr = wave >> 1, wc = wave & 1;
    int m0 = tm * BM;
    int n0 = tn * BN;

    // ---- Stage full K. Slot idx = tid + 256*i -> row = 8i + (tid>>5),
    // col-slot s = tid&31, global chunk gsrc = s ^ (row&31).
    // LDS dest byte = idx*16 = i*4096 + wave*1024 (+ lane*16 by HW).
    int a5 = tid & 31;
    int b3 = tid >> 5;
#pragma unroll
    for (int i = 0; i < 16; ++i) {
        int row = 8 * i + b3;
        int gsrc = a5 ^ (((8 * i) & 31) | b3);
        int grow = m0 + row; if (grow >= M) grow = M - 1;
        const int8_t* srcq = Qq + (size_t)grow * RANK + gsrc * 16;
        __builtin_amdgcn_global_load_lds((const AS1 uint32_t*)srcq,
            (AS3 uint32_t*)(Qs + i * 4096 + wave * 1024), 16, 0, 0);
        const int8_t* srca = Ap + (size_t)(n0 + row) * RANK + gsrc * 16;
        __builtin_amdgcn_global_load_lds((const AS1 uint32_t*)srca,
            (AS3 uint32_t*)(As + i * 4096 + wave * 1024), 16, 0, 0);
    }
    __syncthreads();   // drains vmcnt(0): all 131072 B resident

    // ---- Compute: 8 K-steps, no barriers. Fragment for K-step ks, quarter
    // g = lane>>4: global chunk gc = ks*4+g at LDS slot gc ^ (row&31).
    v4i acc[4][4] = {};
    int g = lane >> 4;
    int rl = lane & 15;
#pragma unroll
    for (int ks = 0; ks < 8; ++ks) {
        v4i aF[4], bF[4];
#pragma unroll
        for (int mi = 0; mi < 4; ++mi) {
            int row = wr * 64 + mi * 16 + rl;
            int s = (ks * 4 + g) ^ (row & 31);
            aF[mi] = *(const v4i*)(Qs + row * RANK + s * 16);
        }
#pragma unroll
        for (int ni = 0; ni < 4; ++ni) {
            int row = wc * 64 + ni * 16 + rl;
            int s = (ks * 4 + g) ^ (row & 31);
            bF[ni] = *(const v4i*)(As + row * RANK + s * 16);
        }
#pragma unroll
        for (int mi = 0; mi < 4; ++mi)
#pragma unroll
            for (int ni = 0; ni < 4; ++ni)
                acc[mi][ni] = __builtin_amdgcn_mfma_i32_16x16x64_i8(
                    aF[mi], bF[ni], acc[mi][ni], 0, 0, 0);
    }

    // ---- Epilogue: dequant + store. C/D: col = lane&15, row = (lane>>4)*4+r.
    int gq = lane >> 4;
    int cn = lane & 15;
#pragma unroll
    for (int mi = 0; mi < 4; ++mi) {
        int mbase = m0 + wr * 64 + mi * 16 + gq * 4;
        float sm[4];
#pragma unroll
        for (int r = 0; r < 4; ++r) {
            int mm = mbase + r;
            sm[r] = (mm < M) ? scales[mm] : 0.f;
        }
#pragma unroll
        for (int ni = 0; ni < 4; ++ni) {
            int n = n0 + wc * 64 + ni * 16 + cn;
            float asc = Ascale[n];
#pragma unroll
            for (int r = 0; r < 4; ++r) {
                int mm = mbase + r;
                if (mm < M)
                    out[(size_t)mm * OUTF + n] = (float)acc[mi][ni][r] * sm[r] * asc;
            }
        }
    }
}

// ---------------------------------------------------------------------------
extern "C" void kernel_launch(void* const* d_in, const int* in_sizes, int n_in,
                              void* d_out, int out_size, void* d_ws, size_t ws_size,
                              hipStream_t stream) {
    const float* new_x  = (const float*)d_in[0];
    const float* cached = (const float*)d_in[1];
    const float* Bw     = (const float*)d_in[2];
    const int*   Ai     = (const int*)d_in[3];
    const float* Ascale = (const float*)d_in[4];

    float* out = (float*)d_out;
    float* out_latent = out + (size_t)MROWS * OUTF;

    const size_t Q_BYTES = (size_t)MROWS * RANK;
    const size_t S_BYTES = (size_t)MROWS * sizeof(float);
    int8_t*  Qq     = (int8_t*)d_ws;
    float*   scales = (float*)((char*)d_ws + Q_BYTES);
    int8_t*  Ap     = (int8_t*)((char*)d_ws + Q_BYTES + S_BYTES);

    k_new_latent<<<512, 256, 0, stream>>>(new_x, Bw, out_latent);
    k_quant<<<SROWS, 256, 0, stream>>>(cached, out_latent, Qq, scales);
    k_packA<<<(OUTF * RANK / 4) / 256, 256, 0, stream>>>(Ai, (uint8_t*)Ap);
    int nt_m = (MROWS + BM - 1) / BM;   // 129
    k_gemm<<<nt_m * NT_N, 256, 0, stream>>>(Qq, Ap, scales, Ascale, out, MROWS);
}

// Round 5
// 155.223 us; speedup vs baseline: 1.4287x; 1.4287x over previous
//
#include <hip/hip_runtime.h>
#include <cstdint>
#include <cstddef>

#define BATCH   4
#define SEQ     4096
#define HIDDEN  4096
#define RANK    512
#define OUTF    4096
#define SROWS   4097              // seq+1
#define MROWS   (BATCH * SROWS)   // 16388

typedef int v4i __attribute__((ext_vector_type(4)));

#define AS1 __attribute__((address_space(1)))
#define AS3 __attribute__((address_space(3)))

// ---------------------------------------------------------------------------
// Kernel 1: new_latent[b][r] = dot(new_x[b,0,:], B_weight[r,:])
// ---------------------------------------------------------------------------
__global__ void k_new_latent(const float* __restrict__ newx,
                             const float* __restrict__ Bw,
                             float* __restrict__ out_latent) {
    int wave = threadIdx.x >> 6;
    int lane = threadIdx.x & 63;
    int pair = blockIdx.x * 4 + wave;   // 0..2047
    int b = pair >> 9;
    int r = pair & 511;
    const float4* x4 = (const float4*)(newx + (size_t)b * HIDDEN);
    const float4* w4 = (const float4*)(Bw + (size_t)r * HIDDEN);
    float sum = 0.f;
#pragma unroll
    for (int j = 0; j < 16; ++j) {
        float4 xv = x4[lane + 64 * j];
        float4 wv = w4[lane + 64 * j];
        sum += xv.x * wv.x + xv.y * wv.y + xv.z * wv.z + xv.w * wv.w;
    }
#pragma unroll
    for (int off = 32; off >= 1; off >>= 1)
        sum += __shfl_xor(sum, off, 64);
    if (lane == 0) {
        out_latent[(size_t)(b * SROWS + SEQ) * RANK + r] = sum;
    }
}

// ---------------------------------------------------------------------------
// Kernel 2: per-row int8 quant (rank=512) + copy cached rows to output.
// ---------------------------------------------------------------------------
__global__ void k_quant(const float* __restrict__ cached,
                        float* __restrict__ out_latent,
                        int8_t* __restrict__ Qq,
                        float* __restrict__ scales) {
    int m = blockIdx.x * 4 + (threadIdx.x >> 6);   // 0..16387
    int lane = threadIdx.x & 63;
    int b = m / SROWS;
    int s = m - b * SROWS;
    const float* src = (s < SEQ) ? (cached + ((size_t)b * SEQ + s) * RANK)
                                 : (out_latent + (size_t)m * RANK);
    float4 v0 = ((const float4*)src)[lane];
    float4 v1 = ((const float4*)src)[64 + lane];
    float am = fmaxf(fmaxf(fmaxf(fabsf(v0.x), fabsf(v0.y)),
                           fmaxf(fabsf(v0.z), fabsf(v0.w))),
                     fmaxf(fmaxf(fabsf(v1.x), fabsf(v1.y)),
                           fmaxf(fabsf(v1.z), fabsf(v1.w))));
#pragma unroll
    for (int off = 32; off >= 1; off >>= 1)
        am = fmaxf(am, __shfl_xor(am, off, 64));
    am = fmaxf(am, 1e-8f);
    float scale = am / 127.0f;

    auto qp = [&](float x) -> uint32_t {
        float r = rintf(x / scale);          // round-half-even, matches jnp.round
        r = fminf(fmaxf(r, -128.0f), 127.0f);
        return (uint32_t)(uint8_t)(int8_t)(int)r;
    };
    uint32_t p0 = qp(v0.x) | (qp(v0.y) << 8) | (qp(v0.z) << 16) | (qp(v0.w) << 24);
    uint32_t p1 = qp(v1.x) | (qp(v1.y) << 8) | (qp(v1.z) << 16) | (qp(v1.w) << 24);
    uint32_t* qrow = (uint32_t*)(Qq + (size_t)m * RANK);
    qrow[lane] = p0;
    qrow[64 + lane] = p1;
    if (s < SEQ) {
        float4* dst = (float4*)(out_latent + (size_t)m * RANK);
        dst[lane] = v0;
        dst[64 + lane] = v1;
    }
    if (lane == 0) scales[m] = scale;
}

// ---------------------------------------------------------------------------
// Kernel 3: pack A_int8 (int32 storage, 4096x512) -> int8 bytes.
// ---------------------------------------------------------------------------
__global__ void k_packA(const int* __restrict__ Ai, uint8_t* __restrict__ Ap) {
    int idx = blockIdx.x * blockDim.x + threadIdx.x;
    int4 v = ((const int4*)Ai)[idx];
    uint32_t p = (uint32_t)(v.x & 0xff) | ((uint32_t)(v.y & 0xff) << 8) |
                 ((uint32_t)(v.z & 0xff) << 16) | ((uint32_t)(v.w & 0xff) << 24);
    ((uint32_t*)Ap)[idx] = p;
}

// ---------------------------------------------------------------------------
// Kernel 4: int8 GEMM + dequant. Double-buffered BK=64, counted vmcnt,
// chunk-column-major LDS:
//   buffer = 512 chunks of 16 B; chunk idx = c*128 + R  (c = 16B chunk of
//   the row's 64 B K-step, R = tile row). Fragment read for quarter g is
//   then 16 consecutive rows at stride 16 B = contiguous 256 B -> no bank
//   conflicts. global_load_lds dest stays linear (idx*16); only the global
//   source address is permuted (per-lane global src is allowed).
// ---------------------------------------------------------------------------
#define BM 128
#define BN 128
#define BK 64
#define NT_N (OUTF / BN)   // 32
#define NKT  (RANK / BK)   // 8

__launch_bounds__(256, 4)
__global__ void k_gemm(const int8_t* __restrict__ Qq,
                       const int8_t* __restrict__ Ap,
                       const float* __restrict__ scales,
                       const float* __restrict__ Ascale,
                       float* __restrict__ out,
                       int M) {
    __shared__ __align__(16) int8_t Qs[2][BM * BK];   // 2 x 8 KiB
    __shared__ __align__(16) int8_t As[2][BN * BK];   // 2 x 8 KiB

    // XCD-bijective blockIdx swizzle (gridDim.x = 4128, % 8 == 0).
    int per = gridDim.x >> 3;
    int bid = blockIdx.x;
    int swz = (bid & 7) * per + (bid >> 3);
    int tn = swz & (NT_N - 1);
    int tm = swz / NT_N;

    int tid = threadIdx.x;
    int lane = tid & 63;
    int wave = tid >> 6;
    int wr = wave >> 1, wc = wave & 1;
    int m0 = tm * BM;
    int n0 = tn * BN;

    // Staging (chunk-column-major): chunk idx = tid + 256*h -> c = idx>>7,
    // R = idx&127. h=0 gives c = tid>>7 (0/1), h=1 gives c+2.
    int cR = tid & 127;
    int cc = tid >> 7;                 // 0 or 1
    int growq = m0 + cR; if (growq >= M) growq = M - 1;
    const int8_t* q0 = Qq + (size_t)growq * RANK + cc * 16;        // h=0
    const int8_t* q1 = q0 + 32;                                    // h=1: c+2
    const int8_t* a0 = Ap + (size_t)(n0 + cR) * RANK + cc * 16;
    const int8_t* a1 = a0 + 32;
    uint32_t w16 = (uint32_t)(wave * 1024);   // wave-uniform LDS byte base

#define STAGE(bufi, kt) do {                                                  \
    int off_ = (kt) * BK;                                                     \
    __builtin_amdgcn_global_load_lds((const AS1 uint32_t*)(q0 + off_),        \
        (AS3 uint32_t*)(&Qs[bufi][0] + w16), 16, 0, 0);                       \
    __builtin_amdgcn_global_load_lds((const AS1 uint32_t*)(q1 + off_),        \
        (AS3 uint32_t*)(&Qs[bufi][0] + w16 + 4096), 16, 0, 0);                \
    __builtin_amdgcn_global_load_lds((const AS1 uint32_t*)(a0 + off_),        \
        (AS3 uint32_t*)(&As[bufi][0] + w16), 16, 0, 0);                       \
    __builtin_amdgcn_global_load_lds((const AS1 uint32_t*)(a1 + off_),        \
        (AS3 uint32_t*)(&As[bufi][0] + w16 + 4096), 16, 0, 0);                \
  } while (0)

    v4i acc[4][4] = {};
    int g = lane >> 4;      // K-quarter = chunk column
    int rl = lane & 15;

    STAGE(0, 0);
#pragma unroll
    for (int kt = 0; kt < NKT; ++kt) {
        int cb = kt & 1;
        if (kt < NKT - 1) {
            STAGE(cb ^ 1, kt + 1);
            asm volatile("s_waitcnt vmcnt(4)" ::: "memory");
        } else {
            asm volatile("s_waitcnt vmcnt(0)" ::: "memory");
        }
        __builtin_amdgcn_s_barrier();   // tile kt fully in LDS

        v4i aF[4], bF[4];
#pragma unroll
        for (int mi = 0; mi < 4; ++mi) {
            int row = wr * 64 + mi * 16 + rl;
            aF[mi] = *(const v4i*)(&Qs[cb][0] + g * 2048 + row * 16);
        }
#pragma unroll
        for (int ni = 0; ni < 4; ++ni) {
            int row = wc * 64 + ni * 16 + rl;
            bF[ni] = *(const v4i*)(&As[cb][0] + g * 2048 + row * 16);
        }
#pragma unroll
        for (int mi = 0; mi < 4; ++mi)
#pragma unroll
            for (int ni = 0; ni < 4; ++ni)
                acc[mi][ni] = __builtin_amdgcn_mfma_i32_16x16x64_i8(
                    aF[mi], bF[ni], acc[mi][ni], 0, 0, 0);

        __builtin_amdgcn_s_barrier();   // reads done before next overwrite
    }
#undef STAGE

    // Epilogue: dequant + store. C/D: col = lane&15, row = (lane>>4)*4+r.
    int gq = lane >> 4;
    int cn = lane & 15;
#pragma unroll
    for (int mi = 0; mi < 4; ++mi) {
        int mbase = m0 + wr * 64 + mi * 16 + gq * 4;
        float sm[4];
#pragma unroll
        for (int r = 0; r < 4; ++r) {
            int mm = mbase + r;
            sm[r] = (mm < M) ? scales[mm] : 0.f;
        }
#pragma unroll
        for (int ni = 0; ni < 4; ++ni) {
            int n = n0 + wc * 64 + ni * 16 + cn;
            float asc = Ascale[n];
#pragma unroll
            for (int r = 0; r < 4; ++r) {
                int mm = mbase + r;
                if (mm < M)
                    out[(size_t)mm * OUTF + n] = (float)acc[mi][ni][r] * sm[r] * asc;
            }
        }
    }
}

// ---------------------------------------------------------------------------
extern "C" void kernel_launch(void* const* d_in, const int* in_sizes, int n_in,
                              void* d_out, int out_size, void* d_ws, size_t ws_size,
                              hipStream_t stream) {
    const float* new_x  = (const float*)d_in[0];
    const float* cached = (const float*)d_in[1];
    const float* Bw     = (const float*)d_in[2];
    const int*   Ai     = (const int*)d_in[3];
    const float* Ascale = (const float*)d_in[4];

    float* out = (float*)d_out;
    float* out_latent = out + (size_t)MROWS * OUTF;

    const size_t Q_BYTES = (size_t)MROWS * RANK;
    const size_t S_BYTES = (size_t)MROWS * sizeof(float);
    int8_t*  Qq     = (int8_t*)d_ws;
    float*   scales = (float*)((char*)d_ws + Q_BYTES);
    int8_t*  Ap     = (int8_t*)((char*)d_ws + Q_BYTES + S_BYTES);

    k_new_latent<<<512, 256, 0, stream>>>(new_x, Bw, out_latent);
    k_quant<<<SROWS, 256, 0, stream>>>(cached, out_latent, Qq, scales);
    k_packA<<<(OUTF * RANK / 4) / 256, 256, 0, stream>>>(Ai, (uint8_t*)Ap);
    int nt_m = (MROWS + BM - 1) / BM;   // 129
    k_gemm<<<nt_m * NT_N, 256, 0, stream>>>(Qq, Ap, scales, Ascale, out, MROWS);
}

// Round 6
// 134.640 us; speedup vs baseline: 1.6471x; 1.1529x over previous
//
#include <hip/hip_runtime.h>
#include <cstdint>
#include <cstddef>

#define BATCH   4
#define SEQ     4096
#define HIDDEN  4096
#define RANK    512
#define OUTF    4096
#define SROWS   4097              // seq+1
#define MROWS   (BATCH * SROWS)   // 16388

typedef int v4i __attribute__((ext_vector_type(4)));

#define AS1 __attribute__((address_space(1)))
#define AS3 __attribute__((address_space(3)))

// ---------------------------------------------------------------------------
// Kernel 1: new_latent[b][r] = dot(new_x[b,0,:], B_weight[r,:])
// ---------------------------------------------------------------------------
__global__ void k_new_latent(const float* __restrict__ newx,
                             const float* __restrict__ Bw,
                             float* __restrict__ out_latent) {
    int wave = threadIdx.x >> 6;
    int lane = threadIdx.x & 63;
    int pair = blockIdx.x * 4 + wave;   // 0..2047
    int b = pair >> 9;
    int r = pair & 511;
    const float4* x4 = (const float4*)(newx + (size_t)b * HIDDEN);
    const float4* w4 = (const float4*)(Bw + (size_t)r * HIDDEN);
    float sum = 0.f;
#pragma unroll
    for (int j = 0; j < 16; ++j) {
        float4 xv = x4[lane + 64 * j];
        float4 wv = w4[lane + 64 * j];
        sum += xv.x * wv.x + xv.y * wv.y + xv.z * wv.z + xv.w * wv.w;
    }
#pragma unroll
    for (int off = 32; off >= 1; off >>= 1)
        sum += __shfl_xor(sum, off, 64);
    if (lane == 0) {
        out_latent[(size_t)(b * SROWS + SEQ) * RANK + r] = sum;
    }
}

// ---------------------------------------------------------------------------
// Kernel 2: per-row int8 quant (rank=512) + copy cached rows to output.
// ---------------------------------------------------------------------------
__global__ void k_quant(const float* __restrict__ cached,
                        float* __restrict__ out_latent,
                        int8_t* __restrict__ Qq,
                        float* __restrict__ scales) {
    int m = blockIdx.x * 4 + (threadIdx.x >> 6);   // 0..16387
    int lane = threadIdx.x & 63;
    int b = m / SROWS;
    int s = m - b * SROWS;
    const float* src = (s < SEQ) ? (cached + ((size_t)b * SEQ + s) * RANK)
                                 : (out_latent + (size_t)m * RANK);
    float4 v0 = ((const float4*)src)[lane];
    float4 v1 = ((const float4*)src)[64 + lane];
    float am = fmaxf(fmaxf(fmaxf(fabsf(v0.x), fabsf(v0.y)),
                           fmaxf(fabsf(v0.z), fabsf(v0.w))),
                     fmaxf(fmaxf(fabsf(v1.x), fabsf(v1.y)),
                           fmaxf(fabsf(v1.z), fabsf(v1.w))));
#pragma unroll
    for (int off = 32; off >= 1; off >>= 1)
        am = fmaxf(am, __shfl_xor(am, off, 64));
    am = fmaxf(am, 1e-8f);
    float scale = am / 127.0f;

    auto qp = [&](float x) -> uint32_t {
        float r = rintf(x / scale);          // round-half-even, matches jnp.round
        r = fminf(fmaxf(r, -128.0f), 127.0f);
        return (uint32_t)(uint8_t)(int8_t)(int)r;
    };
    uint32_t p0 = qp(v0.x) | (qp(v0.y) << 8) | (qp(v0.z) << 16) | (qp(v0.w) << 24);
    uint32_t p1 = qp(v1.x) | (qp(v1.y) << 8) | (qp(v1.z) << 16) | (qp(v1.w) << 24);
    uint32_t* qrow = (uint32_t*)(Qq + (size_t)m * RANK);
    qrow[lane] = p0;
    qrow[64 + lane] = p1;
    if (s < SEQ) {
        float4* dst = (float4*)(out_latent + (size_t)m * RANK);
        dst[lane] = v0;
        dst[64 + lane] = v1;
    }
    if (lane == 0) scales[m] = scale;
}

// ---------------------------------------------------------------------------
// Kernel 3: pack A_int8 (int32 storage, 4096x512) -> int8 bytes.
// ---------------------------------------------------------------------------
__global__ void k_packA(const int* __restrict__ Ai, uint8_t* __restrict__ Ap) {
    int idx = blockIdx.x * blockDim.x + threadIdx.x;
    int4 v = ((const int4*)Ai)[idx];
    uint32_t p = (uint32_t)(v.x & 0xff) | ((uint32_t)(v.y & 0xff) << 8) |
                 ((uint32_t)(v.z & 0xff) << 16) | ((uint32_t)(v.w & 0xff) << 24);
    ((uint32_t*)Ap)[idx] = p;
}

// ---------------------------------------------------------------------------
// Kernel 4: int8 GEMM + dequant. Double-buffered BK=64, counted vmcnt.
// Row-major LDS (64 B rows, coalesced staging: 4 lanes cover one row's 64 B)
// with pair-XOR chunk swizzle to kill ds_read_b128 bank conflicts:
//   LDS[R][s] = global[R][s ^ ((R>>1)&3)]   (involution, both sides)
// Read for K-quarter g of row R: slot g ^ ((R>>1)&3) -> 16 lanes spread over
// all 32 banks, 2 lanes/span = conflict-free (m136: 2-way is free).
// ---------------------------------------------------------------------------
#define BM 128
#define BN 128
#define BK 64
#define NT_N (OUTF / BN)   // 32
#define NKT  (RANK / BK)   // 8

__launch_bounds__(256, 4)
__global__ void k_gemm(const int8_t* __restrict__ Qq,
                       const int8_t* __restrict__ Ap,
                       const float* __restrict__ scales,
                       const float* __restrict__ Ascale,
                       float* __restrict__ out,
                       int M) {
    __shared__ __align__(16) int8_t Qs[2][BM * BK];   // 2 x 8 KiB
    __shared__ __align__(16) int8_t As[2][BN * BK];   // 2 x 8 KiB

    // XCD-bijective blockIdx swizzle (gridDim.x = 4128, % 8 == 0).
    int per = gridDim.x >> 3;
    int bid = blockIdx.x;
    int swz = (bid & 7) * per + (bid >> 3);
    int tn = swz & (NT_N - 1);
    int tm = swz / NT_N;

    int tid = threadIdx.x;
    int lane = tid & 63;
    int wave = tid >> 6;
    int wr = wave >> 1, wc = wave & 1;
    int m0 = tm * BM;
    int n0 = tn * BN;

    // Staging: thread tid -> rows R = tid>>2 and R+64, LDS chunk slot
    // s = tid&3, global chunk c = s ^ ((R>>1)&3). (R+64 has same key.)
    // LDS dest linear: chunk idx = tid + 256*h at byte idx*16.
    int R0 = tid >> 2;
    int cg = (tid & 3) ^ ((tid >> 3) & 3);   // swizzled global chunk
    int grow0 = m0 + R0;       if (grow0 >= M) grow0 = M - 1;
    int grow1 = m0 + R0 + 64;  if (grow1 >= M) grow1 = M - 1;
    const int8_t* q0 = Qq + (size_t)grow0 * RANK + cg * 16;
    const int8_t* q1 = Qq + (size_t)grow1 * RANK + cg * 16;
    const int8_t* a0 = Ap + (size_t)(n0 + R0) * RANK + cg * 16;
    const int8_t* a1 = Ap + (size_t)(n0 + R0 + 64) * RANK + cg * 16;
    uint32_t w16 = (uint32_t)(wave * 1024);   // wave-uniform LDS byte base

#define STAGE(bufi, kt) do {                                                  \
    int off_ = (kt) * BK;                                                     \
    __builtin_amdgcn_global_load_lds((const AS1 uint32_t*)(q0 + off_),        \
        (AS3 uint32_t*)(&Qs[bufi][0] + w16), 16, 0, 0);                       \
    __builtin_amdgcn_global_load_lds((const AS1 uint32_t*)(q1 + off_),        \
        (AS3 uint32_t*)(&Qs[bufi][0] + w16 + 4096), 16, 0, 0);                \
    __builtin_amdgcn_global_load_lds((const AS1 uint32_t*)(a0 + off_),        \
        (AS3 uint32_t*)(&As[bufi][0] + w16), 16, 0, 0);                       \
    __builtin_amdgcn_global_load_lds((const AS1 uint32_t*)(a1 + off_),        \
        (AS3 uint32_t*)(&As[bufi][0] + w16 + 4096), 16, 0, 0);                \
  } while (0)

    v4i acc[4][4] = {};
    int g = lane >> 4;                 // K-quarter
    int rl = lane & 15;
    int sl = g ^ ((rl >> 1) & 3);      // swizzled LDS chunk slot (row-key = rl-key)

    STAGE(0, 0);
#pragma unroll
    for (int kt = 0; kt < NKT; ++kt) {
        int cb = kt & 1;
        if (kt < NKT - 1) {
            STAGE(cb ^ 1, kt + 1);
            asm volatile("s_waitcnt vmcnt(4)" ::: "memory");
        } else {
            asm volatile("s_waitcnt vmcnt(0)" ::: "memory");
        }
        __builtin_amdgcn_s_barrier();   // tile kt fully in LDS

        v4i aF[4], bF[4];
#pragma unroll
        for (int mi = 0; mi < 4; ++mi) {
            int row = wr * 64 + mi * 16 + rl;
            aF[mi] = *(const v4i*)(&Qs[cb][0] + row * BK + sl * 16);
        }
#pragma unroll
        for (int ni = 0; ni < 4; ++ni) {
            int row = wc * 64 + ni * 16 + rl;
            bF[ni] = *(const v4i*)(&As[cb][0] + row * BK + sl * 16);
        }
#pragma unroll
        for (int mi = 0; mi < 4; ++mi)
#pragma unroll
            for (int ni = 0; ni < 4; ++ni)
                acc[mi][ni] = __builtin_amdgcn_mfma_i32_16x16x64_i8(
                    aF[mi], bF[ni], acc[mi][ni], 0, 0, 0);

        __builtin_amdgcn_s_barrier();   // reads done before next overwrite
    }
#undef STAGE

    // Epilogue: dequant + store. C/D: col = lane&15, row = (lane>>4)*4+r.
    int gq = lane >> 4;
    int cn = lane & 15;
#pragma unroll
    for (int mi = 0; mi < 4; ++mi) {
        int mbase = m0 + wr * 64 + mi * 16 + gq * 4;
        float sm[4];
#pragma unroll
        for (int r = 0; r < 4; ++r) {
            int mm = mbase + r;
            sm[r] = (mm < M) ? scales[mm] : 0.f;
        }
#pragma unroll
        for (int ni = 0; ni < 4; ++ni) {
            int n = n0 + wc * 64 + ni * 16 + cn;
            float asc = Ascale[n];
#pragma unroll
            for (int r = 0; r < 4; ++r) {
                int mm = mbase + r;
                if (mm < M)
                    out[(size_t)mm * OUTF + n] = (float)acc[mi][ni][r] * sm[r] * asc;
            }
        }
    }
}

// ---------------------------------------------------------------------------
extern "C" void kernel_launch(void* const* d_in, const int* in_sizes, int n_in,
                              void* d_out, int out_size, void* d_ws, size_t ws_size,
                              hipStream_t stream) {
    const float* new_x  = (const float*)d_in[0];
    const float* cached = (const float*)d_in[1];
    const float* Bw     = (const float*)d_in[2];
    const int*   Ai     = (const int*)d_in[3];
    const float* Ascale = (const float*)d_in[4];

    float* out = (float*)d_out;
    float* out_latent = out + (size_t)MROWS * OUTF;

    const size_t Q_BYTES = (size_t)MROWS * RANK;
    const size_t S_BYTES = (size_t)MROWS * sizeof(float);
    int8_t*  Qq     = (int8_t*)d_ws;
    float*   scales = (float*)((char*)d_ws + Q_BYTES);
    int8_t*  Ap     = (int8_t*)((char*)d_ws + Q_BYTES + S_BYTES);

    k_new_latent<<<512, 256, 0, stream>>>(new_x, Bw, out_latent);
    k_quant<<<SROWS, 256, 0, stream>>>(cached, out_latent, Qq, scales);
    k_packA<<<(OUTF * RANK / 4) / 256, 256, 0, stream>>>(Ai, (uint8_t*)Ap);
    int nt_m = (MROWS + BM - 1) / BM;   // 129
    k_gemm<<<nt_m * NT_N, 256, 0, stream>>>(Qq, Ap, scales, Ascale, out, MROWS);
}